// Round 10
// baseline (231.544 us; speedup 1.0000x reference)
//
#include <hip/hip_runtime.h>

// ---------------------------------------------------------------------------
// MoE cross-attention decoder layer on MI355X (gfx950), bf16 MFMA pipeline.
// R10: gemm_og now applies the gate weight per expert and atomicAdd-
// accumulates into a 1.6 MB f32 MIX buffer (OUTf round-trip eliminated);
// finalize = tgt + MIX + LayerNorm. Everything else unchanged from R9.
// ---------------------------------------------------------------------------

typedef __bf16 bf16x8 __attribute__((ext_vector_type(8)));
typedef float f32x4 __attribute__((ext_vector_type(4)));
typedef unsigned int u32x4 __attribute__((ext_vector_type(4)));
typedef unsigned int u32x2 __attribute__((ext_vector_type(2)));
typedef unsigned short u16x4 __attribute__((ext_vector_type(4)));
typedef unsigned short us;

__device__ __forceinline__ us f2bf(float f) {
    unsigned u = __builtin_bit_cast(unsigned, f);
    u += 0x7FFFu + ((u >> 16) & 1u);
    return (us)(u >> 16);
}

__device__ __forceinline__ unsigned pack2(float lo, float hi) {
    return (unsigned)f2bf(lo) | ((unsigned)f2bf(hi) << 16);
}

__device__ __forceinline__ float bf2f(us v) {
    unsigned u = ((unsigned)v) << 16;
    return __builtin_bit_cast(float, u);
}

__device__ __forceinline__ bf16x8 ld_bf8(const us* p) {
    return __builtin_bit_cast(bf16x8, *reinterpret_cast<const u32x4*>(p));
}

__device__ __forceinline__ void gld_lds16(const us* g, us* l) {
    __builtin_amdgcn_global_load_lds(
        (const __attribute__((address_space(1))) unsigned int*)g,
        (__attribute__((address_space(3))) unsigned int*)l, 16, 0, 0);
}

// ---------------- fused converts + gate softmax ----------------------------
__launch_bounds__(256)
__global__ void cvt_all(const float* __restrict__ tgt, const float* __restrict__ qpos,
                        const float* __restrict__ mem, const float* __restrict__ pos,
                        const float* __restrict__ w_in, const float* __restrict__ w_out,
                        const float* __restrict__ w_gate, const float* __restrict__ b_gate,
                        us* __restrict__ Aq, us* __restrict__ Ak, us* __restrict__ Av,
                        us* __restrict__ Wb, us* __restrict__ WOb,
                        float* __restrict__ Gate)
{
    const int bid = blockIdx.x;
    const int tid = threadIdx.x;
    if (bid < 400) {
        const int i = bid * 256 + tid;
        const int lane = tid & 63;
        const int row = i >> 6;                 // = 4*bid + wave
        f32x4 a = reinterpret_cast<const f32x4*>(tgt)[i];
        f32x4 b = reinterpret_cast<const f32x4*>(qpos)[i];
        u16x4 r;
#pragma unroll
        for (int j = 0; j < 4; ++j) r[j] = f2bf(a[j] + b[j]);
        reinterpret_cast<u16x4*>(Aq)[i] = r;
        float g[5];
#pragma unroll
        for (int e = 0; e < 5; ++e) {
            f32x4 wg = *reinterpret_cast<const f32x4*>(w_gate + e * 256 + 4 * lane);
            float p = a[0] * wg[0] + a[1] * wg[1] + a[2] * wg[2] + a[3] * wg[3];
#pragma unroll
            for (int off = 32; off >= 1; off >>= 1) p += __shfl_xor(p, off, 64);
            g[e] = p + b_gate[e];
        }
        float mx = g[0];
#pragma unroll
        for (int e = 1; e < 5; ++e) mx = fmaxf(mx, g[e]);
        float sm = 0.0f;
#pragma unroll
        for (int e = 0; e < 5; ++e) { g[e] = __expf(g[e] - mx); sm += g[e]; }
        const float invs = 1.0f / sm;
        if (lane == 0) {
#pragma unroll
            for (int e = 0; e < 5; ++e) Gate[row * 5 + e] = g[e] * invs;
        }
    } else if (bid < 4496) {
        int i = (bid - 400) * 256 + tid;
        f32x4 m = reinterpret_cast<const f32x4*>(mem)[i];
        f32x4 p = reinterpret_cast<const f32x4*>(pos)[i];
        u16x4 rk, rv;
#pragma unroll
        for (int j = 0; j < 4; ++j) { rk[j] = f2bf(m[j] + p[j]); rv[j] = f2bf(m[j]); }
        reinterpret_cast<u16x4*>(Ak)[i] = rk;
        reinterpret_cast<u16x4*>(Av)[i] = rv;
    } else if (bid < 5456) {
        int i = (bid - 4496) * 256 + tid;
        f32x4 a = reinterpret_cast<const f32x4*>(w_in)[i];
        u16x4 r;
#pragma unroll
        for (int j = 0; j < 4; ++j) r[j] = f2bf(a[j]);
        reinterpret_cast<u16x4*>(Wb)[i] = r;
    } else {
        int i = (bid - 5456) * 256 + tid;
        f32x4 a = reinterpret_cast<const f32x4*>(w_out)[i];
        u16x4 r;
#pragma unroll
        for (int j = 0; j < 4; ++j) r[j] = f2bf(a[j]);
        reinterpret_cast<u16x4*>(WOb)[i] = r;
    }
}

// ---------------- GEMM body (R8, unchanged): C = A * W^T -------------------
template <bool BF16OUT>
__device__ __forceinline__ void gemm_body(const us* __restrict__ A,
                                          const us* __restrict__ W,
                                          const float* __restrict__ bias,
                                          void* __restrict__ Cout,
                                          float scale, int M)
{
    const int row0 = blockIdx.x * 128;
    const int col0 = blockIdx.y * 128;
    __shared__ us As[2 * 8192];
    __shared__ us Bs[2 * 8192];
    const int tid  = threadIdx.x;
    const int lane = tid & 63;
    const int w    = tid >> 6;
    const int l15  = lane & 15;
    const int quad = lane >> 4;
    const int wm   = (w >> 1) * 64;
    const int wn   = (w & 1) * 64;
    const int srow = lane >> 3;
    const int gofs = ((lane & 7) ^ srow) * 8;

#pragma unroll
    for (int cc = 0; cc < 4; ++cc) {
        const int c = w * 4 + cc;
        const int row = c * 8 + srow;
        gld_lds16(A + (size_t)(row0 + row) * 256 + gofs, &As[c * 512]);
        gld_lds16(W + (size_t)(col0 + row) * 256 + gofs, &Bs[c * 512]);
    }
    __syncthreads();

    f32x4 acc[4][4] = {};

#pragma unroll
    for (int kt = 0; kt < 4; ++kt) {
        const int cur = (kt & 1) * 8192;
        if (kt < 3) {
            const int nxt = ((kt + 1) & 1) * 8192;
            const int k0 = (kt + 1) * 64;
#pragma unroll
            for (int cc = 0; cc < 4; ++cc) {
                const int c = w * 4 + cc;
                const int row = c * 8 + srow;
                gld_lds16(A + (size_t)(row0 + row) * 256 + k0 + gofs, &As[nxt + c * 512]);
                gld_lds16(W + (size_t)(col0 + row) * 256 + k0 + gofs, &Bs[nxt + c * 512]);
            }
        }
#pragma unroll
        for (int kh = 0; kh < 2; ++kh) {
            bf16x8 af[4], bf[4];
#pragma unroll
            for (int mi = 0; mi < 4; ++mi) {
                const int row = wm + mi * 16 + l15;
                const int seg = (kh * 4 + quad) ^ (row & 7);
                af[mi] = ld_bf8(&As[cur + row * 64 + seg * 8]);
            }
#pragma unroll
            for (int ni = 0; ni < 4; ++ni) {
                const int col = wn + ni * 16 + l15;
                const int seg = (kh * 4 + quad) ^ (col & 7);
                bf[ni] = ld_bf8(&Bs[cur + col * 64 + seg * 8]);
            }
#pragma unroll
            for (int mi = 0; mi < 4; ++mi)
#pragma unroll
                for (int ni = 0; ni < 4; ++ni)
                    acc[mi][ni] = __builtin_amdgcn_mfma_f32_16x16x32_bf16(bf[ni], af[mi], acc[mi][ni], 0, 0, 0);
        }
        if (kt < 3) __syncthreads();
    }

#pragma unroll
    for (int mi = 0; mi < 4; ++mi) {
        const int row = row0 + wm + mi * 16 + l15;
        if (row < M) {
#pragma unroll
            for (int ni = 0; ni < 4; ++ni) {
                const int colb = col0 + wn + ni * 16 + quad * 4;
                const f32x4 b4 = *reinterpret_cast<const f32x4*>(bias + colb);
                if constexpr (BF16OUT) {
                    u32x2 pk;
                    pk[0] = pack2((acc[mi][ni][0] + b4[0]) * scale,
                                  (acc[mi][ni][1] + b4[1]) * scale);
                    pk[1] = pack2((acc[mi][ni][2] + b4[2]) * scale,
                                  (acc[mi][ni][3] + b4[3]) * scale);
                    *reinterpret_cast<u32x2*>(reinterpret_cast<us*>(Cout) + (size_t)row * 256 + colb) = pk;
                } else {
                    f32x4 v;
#pragma unroll
                    for (int r = 0; r < 4; ++r) v[r] = (acc[mi][ni][r] + b4[r]) * scale;
                    *reinterpret_cast<f32x4*>(reinterpret_cast<float*>(Cout) + (size_t)row * 256 + colb) = v;
                }
            }
        }
    }
}

// merged Q/K/V projection: z 0..4 = Q (x<13), 5..9 = K, 10..14 = V
__launch_bounds__(256)
__global__ void gemm_qkv(const us* __restrict__ Aq, const us* __restrict__ Ak,
                         const us* __restrict__ Av, const us* __restrict__ Wb,
                         const float* __restrict__ b_in,
                         us* __restrict__ Qb, us* __restrict__ Kb, us* __restrict__ Vb)
{
    const int z = blockIdx.z;
    if (z < 5) {
        if (blockIdx.x >= 13) return;
        gemm_body<true>(Aq, Wb + (size_t)z * 196608, b_in + (size_t)z * 768,
                        Qb + (size_t)z * 409600, 0.17677669529663687f, 1600);
    } else if (z < 10) {
        const int e = z - 5;
        gemm_body<true>(Ak, Wb + 65536 + (size_t)e * 196608, b_in + (size_t)e * 768 + 256,
                        Kb + (size_t)e * 4194304, 1.0f, 16384);
    } else {
        const int e = z - 10;
        gemm_body<true>(Av, Wb + 131072 + (size_t)e * 196608, b_in + (size_t)e * 768 + 512,
                        Vb + (size_t)e * 4194304, 1.0f, 16384);
    }
}

// ---------------- out-proj GEMM: fused combine + gate-weighted atomic mix --
// A-tile built on the fly: CTX = (sum_s PO_s) / (sum_s PL_s), bf16 packed,
// ds_write_b128. Epilogue: (acc + bias) * Gate[row][e] atomicAdd -> MIX.
__launch_bounds__(256)
__global__ void gemm_og(const us* __restrict__ PO, const float* __restrict__ PL,
                        const us* __restrict__ WOb, const float* __restrict__ b_out,
                        const float* __restrict__ Gate, float* __restrict__ MIX)
{
    const int e = blockIdx.z;
    const us* W = WOb + (size_t)e * 65536;
    const float* bias = b_out + (size_t)e * 256;

    const int row0 = blockIdx.x * 128;
    const int col0 = blockIdx.y * 128;
    __shared__ us As[2 * 8192];
    __shared__ us Bs[2 * 8192];
    const int tid  = threadIdx.x;
    const int lane = tid & 63;
    const int w    = tid >> 6;
    const int l15  = lane & 15;
    const int quad = lane >> 4;
    const int wm   = (w >> 1) * 64;
    const int wn   = (w & 1) * 64;
    const int srow = lane >> 3;
    const int gofs = ((lane & 7) ^ srow) * 8;

    u32x4 POr[4][4];   // [chunk][split]
    float Lr[4];

    auto loadA = [&](int kt) {
#pragma unroll
        for (int cc = 0; cc < 4; ++cc) {
            const int c = w * 4 + cc;
            int grow = row0 + c * 8 + srow;
            if (grow > 1599) grow = 1599;
            const int d0 = kt * 64 + gofs;
            const size_t base = (size_t)e * 409600 + (size_t)grow * 256 + d0;
#pragma unroll
            for (int s = 0; s < 4; ++s)
                POr[cc][s] = *reinterpret_cast<const u32x4*>(PO + base + (size_t)s * 2048000);
            const int l = grow >> 4, bb = grow & 15, h = d0 >> 5;
            float L = 0.0f;
#pragma unroll
            for (int s = 0; s < 4; ++s)
                L += PL[((((size_t)s * 5 + e) * 16 + bb) * 8 + h) * 128 + l];
            Lr[cc] = L;
        }
    };
    auto writeA = [&](int buf) {
#pragma unroll
        for (int cc = 0; cc < 4; ++cc) {
            const float inv = 1.0f / Lr[cc];
            u32x4 pk;
#pragma unroll
            for (int j = 0; j < 4; ++j) {
                float v0 = 0.0f, v1 = 0.0f;
#pragma unroll
                for (int s = 0; s < 4; ++s) {
                    const unsigned u = POr[cc][s][j];
                    v0 += __builtin_bit_cast(float, u << 16);
                    v1 += __builtin_bit_cast(float, u & 0xffff0000u);
                }
                pk[j] = pack2(v0 * inv, v1 * inv);
            }
            *reinterpret_cast<u32x4*>(&As[buf * 8192 + (w * 4 + cc) * 512 + lane * 8]) = pk;
        }
    };
    auto loadW = [&](int buf, int kt) {
#pragma unroll
        for (int cc = 0; cc < 4; ++cc) {
            const int c = w * 4 + cc;
            const int row = c * 8 + srow;
            gld_lds16(W + (size_t)(col0 + row) * 256 + kt * 64 + gofs,
                      &Bs[buf * 8192 + c * 512]);
        }
    };

    loadA(0);
    loadW(0, 0);
    writeA(0);
    __syncthreads();

    f32x4 acc[4][4] = {};

#pragma unroll
    for (int kt = 0; kt < 4; ++kt) {
        const int cur = kt & 1;
        if (kt < 3) {
            loadA(kt + 1);
            loadW(cur ^ 1, kt + 1);
        }
#pragma unroll
        for (int kh = 0; kh < 2; ++kh) {
            bf16x8 af[4], bf[4];
#pragma unroll
            for (int mi = 0; mi < 4; ++mi) {
                const int row = wm + mi * 16 + l15;
                const int seg = (kh * 4 + quad) ^ (row & 7);
                af[mi] = ld_bf8(&As[cur * 8192 + row * 64 + seg * 8]);
            }
#pragma unroll
            for (int ni = 0; ni < 4; ++ni) {
                const int col = wn + ni * 16 + l15;
                const int seg = (kh * 4 + quad) ^ (col & 7);
                bf[ni] = ld_bf8(&Bs[cur * 8192 + col * 64 + seg * 8]);
            }
#pragma unroll
            for (int mi = 0; mi < 4; ++mi)
#pragma unroll
                for (int ni = 0; ni < 4; ++ni)
                    acc[mi][ni] = __builtin_amdgcn_mfma_f32_16x16x32_bf16(bf[ni], af[mi], acc[mi][ni], 0, 0, 0);
        }
        if (kt < 3) {
            writeA(cur ^ 1);
            __syncthreads();
        }
    }

#pragma unroll
    for (int mi = 0; mi < 4; ++mi) {
        const int row = row0 + wm + mi * 16 + l15;
        if (row < 1600) {
            const float ge = Gate[row * 5 + e];
            float* mp = MIX + (size_t)row * 256;
#pragma unroll
            for (int ni = 0; ni < 4; ++ni) {
                const int colb = col0 + wn + ni * 16 + quad * 4;
                const f32x4 b4 = *reinterpret_cast<const f32x4*>(bias + colb);
#pragma unroll
                for (int r = 0; r < 4; ++r)
                    atomicAdd(mp + colb + r, (acc[mi][ni][r] + b4[r]) * ge);
            }
        }
    }
}

// ---------------- split-K attention (unchanged from R4/R8) -----------------
__device__ __forceinline__ int vrow(int d) { return d * 264 + 8 * (d >> 3); }

__launch_bounds__(512)
__global__ void attn(const us* __restrict__ Qb, const us* __restrict__ Kb,
                     const us* __restrict__ Vb, us* __restrict__ PO,
                     float* __restrict__ PL)
{
    const int h = blockIdx.x;
    const int z = blockIdx.y;
    const int s = blockIdx.z;
    const int e = z >> 4, b = z & 15;
    const int tid  = threadIdx.x;
    const int w    = tid >> 6;
    const int lane = tid & 63;
    const int l15  = lane & 15, quad = lane >> 4;
    __shared__ us Ks[256 * 32];
    __shared__ us Vs[8464];
    __shared__ us Ps[7][16 * 40];

    const int key0 = s * 256;
    {
        const int kl  = lane >> 2;
        const int seg = lane & 3;
        const us* kg = Kb + ((size_t)((e * 1024 + key0 + w * 16 + kl) * 16 + b)) * 256
                          + h * 32 + seg * 8;
        gld_lds16(kg, &Ks[w * 512]);
        gld_lds16(kg + (size_t)128 * 16 * 256, &Ks[4096 + w * 512]);

        const int kv = tid >> 2;
        const int sg = tid & 3;
        const us* vg = Vb + ((size_t)((e * 1024 + key0 + kv) * 16 + b)) * 256
                          + h * 32 + sg * 8;
        u32x4 v0 = *reinterpret_cast<const u32x4*>(vg);
        u32x4 v1 = *reinterpret_cast<const u32x4*>(vg + (size_t)128 * 16 * 256);
#pragma unroll
        for (int j = 0; j < 4; ++j) {
            const int d0 = sg * 8 + 2 * j;
            const int e0 = vrow(d0);
            const int e1 = e0 + 264;
            Vs[e0 + kv]       = (us)(v0[j] & 0xffff);
            Vs[e1 + kv]       = (us)(v0[j] >> 16);
            Vs[e0 + 128 + kv] = (us)(v1[j] & 0xffff);
            Vs[e1 + 128 + kv] = (us)(v1[j] >> 16);
        }
    }
    u32x4 qraw = {0u, 0u, 0u, 0u};
    if (w < 7) {
        const int l = w * 16 + l15;
        if (l < 100)
            qraw = *reinterpret_cast<const u32x4*>(
                Qb + ((size_t)((e * 100 + l) * 16 + b)) * 256 + h * 32 + quad * 8);
    }
    const bf16x8 qf = __builtin_bit_cast(bf16x8, qraw);

    __syncthreads();

    if (w >= 7) return;

    const f32x4 zacc = {};
    f32x4 o0 = {}, o1 = {};
    float lsum = 0.0f;

    for (int c = 0; c < 8; ++c) {
        bf16x8 kf0 = ld_bf8(&Ks[(c * 32 + l15) * 32 + quad * 8]);
        bf16x8 kf1 = ld_bf8(&Ks[(c * 32 + 16 + l15) * 32 + quad * 8]);
        f32x4 s0 = __builtin_amdgcn_mfma_f32_16x16x32_bf16(kf0, qf, zacc, 0, 0, 0);
        f32x4 s1 = __builtin_amdgcn_mfma_f32_16x16x32_bf16(kf1, qf, zacc, 0, 0, 0);
        float p0[4], p1[4];
#pragma unroll
        for (int r = 0; r < 4; ++r) {
            p0[r] = __expf(s0[r]);
            p1[r] = __expf(s1[r]);
            lsum += p0[r] + p1[r];
        }
        u32x2 w0, w1;
        w0[0] = pack2(p0[0], p0[1]);
        w0[1] = pack2(p0[2], p0[3]);
        w1[0] = pack2(p1[0], p1[1]);
        w1[1] = pack2(p1[2], p1[3]);
        *reinterpret_cast<u32x2*>(&Ps[w][l15 * 40 + quad * 4])      = w0;
        *reinterpret_cast<u32x2*>(&Ps[w][l15 * 40 + 16 + quad * 4]) = w1;
        bf16x8 pf  = ld_bf8(&Ps[w][l15 * 40 + quad * 8]);
        bf16x8 vf0 = ld_bf8(&Vs[vrow(l15) + c * 32 + quad * 8]);
        bf16x8 vf1 = ld_bf8(&Vs[vrow(16 + l15) + c * 32 + quad * 8]);
        o0 = __builtin_amdgcn_mfma_f32_16x16x32_bf16(pf, vf0, o0, 0, 0, 0);
        o1 = __builtin_amdgcn_mfma_f32_16x16x32_bf16(pf, vf1, o1, 0, 0, 0);
    }

    lsum += __shfl_xor(lsum, 16, 64);
    lsum += __shfl_xor(lsum, 32, 64);

#pragma unroll
    for (int r = 0; r < 4; ++r) {
        const int row = w * 16 + quad * 4 + r;
        if (row < 100) {
            const size_t o = (((size_t)((s * 5 + e) * 100 + row)) * 16 + b) * 256 + h * 32;
            PO[o + l15]      = f2bf(o0[r]);
            PO[o + 16 + l15] = f2bf(o1[r]);
        }
    }
    const int q = w * 16 + l15;
    if (quad == 0 && q < 100)
        PL[((((size_t)s * 5 + e) * 16 + b) * 8 + h) * 128 + q] = lsum;
}

// ---------------- residual + LayerNorm (MIX already gate-weighted) ---------
__launch_bounds__(256)
__global__ void finalize(const float* __restrict__ tgt, const float* __restrict__ MIX,
                         const float* __restrict__ gamma, const float* __restrict__ beta,
                         float* __restrict__ out)
{
    const int row = blockIdx.x;
    const int d = threadIdx.x;
    __shared__ float red[8];
    const float x = tgt[(size_t)row * 256 + d] + MIX[(size_t)row * 256 + d];

    float p1 = x, p2 = x * x;
#pragma unroll
    for (int off = 32; off >= 1; off >>= 1) {
        p1 += __shfl_xor(p1, off, 64);
        p2 += __shfl_xor(p2, off, 64);
    }
    if ((d & 63) == 0) { red[d >> 6] = p1; red[4 + (d >> 6)] = p2; }
    __syncthreads();
    const float mean = (red[0] + red[1] + red[2] + red[3]) * (1.0f / 256.0f);
    const float msq  = (red[4] + red[5] + red[6] + red[7]) * (1.0f / 256.0f);
    const float var  = msq - mean * mean;

    out[(size_t)row * 256 + d] = (x - mean) * rsqrtf(var + 1e-5f) * gamma[d] + beta[d];
}

// ---------------------------------------------------------------------------
extern "C" void kernel_launch(void* const* d_in, const int* in_sizes, int n_in,
                              void* d_out, int out_size, void* d_ws, size_t ws_size,
                              hipStream_t stream)
{
    const float* tgt    = (const float*)d_in[0];
    const float* mem    = (const float*)d_in[1];
    const float* qpos   = (const float*)d_in[2];
    const float* pos    = (const float*)d_in[3];
    const float* w_in   = (const float*)d_in[4];
    const float* b_in   = (const float*)d_in[5];
    const float* w_out  = (const float*)d_in[6];
    const float* b_out  = (const float*)d_in[7];
    const float* w_gate = (const float*)d_in[8];
    const float* b_gate = (const float*)d_in[9];
    const float* ln_g   = (const float*)d_in[10];
    const float* ln_b   = (const float*)d_in[11];
    float* out = (float*)d_out;

    char* p = (char*)d_ws;
    auto alloc = [&](size_t n) { char* r = p; p += (n + 255) & ~(size_t)255; return r; };

    us* Aq   = (us*)alloc(409600ull * 2);       // dead after gemm_qkv
    us* Ak   = (us*)alloc(4194304ull * 2);      // dead after gemm_qkv
    us* Av   = (us*)alloc(4194304ull * 2);      // dead after gemm_qkv
    us* Wb   = (us*)alloc(983040ull * 2);
    us* WOb  = (us*)alloc(327680ull * 2);
    us* Qb   = (us*)alloc(5ull * 409600 * 2);
    us* Kb   = (us*)alloc(5ull * 4194304 * 2);
    us* Vb   = (us*)alloc(5ull * 4194304 * 2);
    float* Gate = (float*)alloc(1600ull * 5 * 4);
    float* MIX  = (float*)alloc(1600ull * 256 * 4);
    // Attention partials alias the dead cvt region (Aq..Av): 16.4+0.33 < 17.7 MB
    us*    PO = (us*)d_ws;                          // [4][5][100][16][256] bf16
    float* PL = (float*)((char*)d_ws + 16384000);   // [4*5*16*8][128] f32

    hipMemsetAsync(MIX, 0, 1600ull * 256 * 4, stream);

    cvt_all<<<5776, 256, 0, stream>>>(tgt, qpos, mem, pos, w_in, w_out,
                                      w_gate, b_gate, Aq, Ak, Av, Wb, WOb, Gate);

    gemm_qkv<<<dim3(128, 2, 15), 256, 0, stream>>>(Aq, Ak, Av, Wb, b_in, Qb, Kb, Vb);

    attn<<<dim3(8, 80, 4), 512, 0, stream>>>(Qb, Kb, Vb, PO, PL);

    gemm_og<<<dim3(13, 2, 5), 256, 0, stream>>>(PO, PL, WOb, b_out, Gate, MIX);

    finalize<<<1600, 256, 0, stream>>>(tgt, MIX, ln_g, ln_b, out);
}